// Round 7
// baseline (213.227 us; speedup 1.0000x reference)
//
#include <hip/hip_runtime.h>
#include <math.h>

// FourierFlow: out[t,n,i] = sum_j expm((M*omega + M0)*t)[i,j] * x[n,j]
// Inputs: x (16384,16) f32 | t (512,) f32 | omega (1,) f32 | M (16,16) f32 | M0 (16,16) f32
// Output: (512, 16384, 16) f32 = 536.9 MB -> write-BW bound (~81 us floor at 6.6 TB/s).
//
// Apply structure (round 7): pure-producer waves. Lane = one x row (persistent
// in 16 VGPRs); wave = one uniform 4-dim output slice, so E[t] loads are
// wave-uniform -> scalar K$ path (s_load), vector pipe sees ONLY stores,
// rotated 4-deep with zero load-side vmcnt waits. No LDS, no barriers.

#define MDIM 16
#define MELEMS 256
#define T_PER_BLOCK 128

typedef float f32x4 __attribute__((ext_vector_type(4)));

// ---------------- Kernel 1: batched 16x16 matrix exponential ----------------
__global__ __launch_bounds__(256) void expm_kernel(
    const float* __restrict__ t,
    const float* __restrict__ omega,
    const float* __restrict__ M,
    const float* __restrict__ M0,
    float* __restrict__ E /* (T,16,16) */) {
  __shared__ float A[MELEMS];
  __shared__ float T[MELEMS];
  __shared__ float rowsum[MDIM];

  const int bt  = blockIdx.x;
  const int tid = threadIdx.x;
  const int i = tid >> 4;
  const int j = tid & 15;

  const float tv = t[bt];
  const float om = omega[0];
  const float a = (M[tid] * om + M0[tid]) * tv;

  // parallel inf-norm: row-sum via 16-lane shuffle butterfly, then max over rows
  float rs = fabsf(a);
  rs += __shfl_xor(rs, 1);
  rs += __shfl_xor(rs, 2);
  rs += __shfl_xor(rs, 4);
  rs += __shfl_xor(rs, 8);
  if (j == 0) rowsum[i] = rs;
  __syncthreads();
  float nrm = 0.f;
#pragma unroll
  for (int r = 0; r < MDIM; ++r) nrm = fmaxf(nrm, rowsum[r]);
  // scaling exponent: nrm / 2^s <= 0.5
  int s = (nrm > 1e-30f) ? (ilogbf(nrm) + 2) : 0;
  if (s < 0) s = 0;

  const float b = ldexpf(a, -s);
  const float ident = (i == j) ? 1.0f : 0.0f;
  A[tid] = b;
  T[tid] = ident;
  __syncthreads();

  // Horner-Taylor: for k = K..1: T = I + (B @ T) / k
  for (int k = 8; k >= 1; --k) {
    float acc = 0.f;
#pragma unroll
    for (int c = 0; c < MDIM; ++c) acc += A[i * MDIM + c] * T[c * MDIM + j];
    __syncthreads();
    T[tid] = ident + acc * (1.0f / (float)k);
    __syncthreads();
  }

  // square s times
  for (int k = 0; k < s; ++k) {
    float acc = 0.f;
#pragma unroll
    for (int c = 0; c < MDIM; ++c) acc += T[i * MDIM + c] * T[c * MDIM + j];
    __syncthreads();
    T[tid] = acc;
    __syncthreads();
  }

  E[(size_t)bt * MELEMS + tid] = T[tid];
}

// ---------------- Kernel 2: out[t,n,:] = E[t] @ x[n,:] ----------------
// grid = (N/64) * (T/128) blocks, 256 threads = 4 waves.
// Wave w handles output dims [4w, 4w+4) for the block's 64 rows; lane l owns
// row rg*64+l with its x row in registers. Per t: 4 wave-uniform 64 B E-row
// loads (scalar path), 64 FMAs, one f32x4 store (lane stride 64 B; the four
// waves fill each 64 B line; L2 merges before writeback). Unroll 4 -> 4-deep
// store rotation, no load-side vmcnt waits in steady state.
__global__ __launch_bounds__(256) void apply_kernel(
    const float* __restrict__ E,  /* (T,16,16) */
    const float* __restrict__ x,  /* (N,16)    */
    float* __restrict__ out,      /* (T,N,16)  */
    int N) {
  const int rgn  = N >> 6;                  // row groups (256)
  const int bx   = blockIdx.x;
  const int rg   = bx % rgn;
  const int tq   = bx / rgn;                // t quarter
  const int lane = threadIdx.x & 63;
  const int w    = __builtin_amdgcn_readfirstlane(threadIdx.x >> 6); // 0..3
  const int row  = rg * 64 + lane;

  // persistent x row -> 16 VGPRs
  float xr[MDIM];
  {
    const f32x4* xrow = (const f32x4*)(x + (size_t)row * MDIM);
#pragma unroll
    for (int q = 0; q < 4; ++q) {
      const f32x4 v = xrow[q];
      xr[q * 4 + 0] = v.x; xr[q * 4 + 1] = v.y;
      xr[q * 4 + 2] = v.z; xr[q * 4 + 3] = v.w;
    }
  }

  const int t0 = tq * T_PER_BLOCK;
  // E rows [4w, 4w+4) of E[t] = 64 consecutive floats at E + t*256 + w*64
  const float* __restrict__ Ew = E + (size_t)w * 64;
  float* __restrict__ ob = out + (size_t)row * MDIM + (size_t)w * 4;

#pragma unroll 4
  for (int tt = 0; tt < T_PER_BLOCK; ++tt) {
    const int t = t0 + tt;
    const float* __restrict__ Eb = Ew + (size_t)t * MELEMS;  // wave-uniform
    float o[4];
#pragma unroll
    for (int j = 0; j < 4; ++j) {
      const float* __restrict__ Er = Eb + j * MDIM;
      float acc = Er[0] * xr[0];
#pragma unroll
      for (int c = 1; c < MDIM; ++c) acc += Er[c] * xr[c];
      o[j] = acc;
    }
    f32x4 v; v.x = o[0]; v.y = o[1]; v.z = o[2]; v.w = o[3];
    *(f32x4*)(ob + (size_t)t * N * MDIM) = v;
  }
}

extern "C" void kernel_launch(void* const* d_in, const int* in_sizes, int n_in,
                              void* d_out, int out_size, void* d_ws, size_t ws_size,
                              hipStream_t stream) {
  const float* x     = (const float*)d_in[0];
  const float* t     = (const float*)d_in[1];
  const float* omega = (const float*)d_in[2];
  const float* M     = (const float*)d_in[3];
  const float* M0    = (const float*)d_in[4];
  float* out = (float*)d_out;

  const int N = in_sizes[0] / MDIM;   // 16384
  const int T = in_sizes[1];          // 512

  float* E = (float*)d_ws;            // T*256 floats = 512 KB

  expm_kernel<<<T, 256, 0, stream>>>(t, omega, M, M0, E);

  const int grid = (N >> 6) * (T / T_PER_BLOCK);  // 256 * 4 = 1024
  apply_kernel<<<grid, 256, 0, stream>>>(E, x, out, N);
}

// Round 8
// 142.967 us; speedup vs baseline: 1.4914x; 1.4914x over previous
//
#include <hip/hip_runtime.h>
#include <math.h>

// FourierFlow: out[t,n,i] = sum_j expm((M*omega + M0)*t)[i,j] * x[n,j]
// Inputs: x (16384,16) f32 | t (512,) f32 | omega (1,) f32 | M (16,16) f32 | M0 (16,16) f32
// Output: (512, 16384, 16) f32 = 536.9 MB -> write-BW bound (~81 us floor at 6.6 TB/s).
//
// Round 8: t-PAIR blocks. Each block holds E[t] AND E[t+1] in registers and
// streams x rows once for BOTH outputs: x read traffic halved, VMEM mix per
// KB stored 5 -> 3 instrs. Store pattern identical to round 6 (contiguous
// 1 KB wave-stores, 2-deep load-before-store rotation).

#define MDIM 16
#define MELEMS 256
#define QUARTERS 4
#define ROWS_PER_BLOCK 4096   // N / QUARTERS
#define KSTEPS 64             // ROWS_PER_BLOCK / 64 rows-per-step

// ---------------- Kernel 1: batched 16x16 matrix exponential ----------------
__global__ __launch_bounds__(256) void expm_kernel(
    const float* __restrict__ t,
    const float* __restrict__ omega,
    const float* __restrict__ M,
    const float* __restrict__ M0,
    float* __restrict__ E /* (T,16,16) */) {
  __shared__ float A[MELEMS];
  __shared__ float T[MELEMS];
  __shared__ float rowsum[MDIM];

  const int bt  = blockIdx.x;
  const int tid = threadIdx.x;
  const int i = tid >> 4;
  const int j = tid & 15;

  const float tv = t[bt];
  const float om = omega[0];
  const float a = (M[tid] * om + M0[tid]) * tv;

  // parallel inf-norm: row-sum via 16-lane shuffle butterfly, then max over rows
  float rs = fabsf(a);
  rs += __shfl_xor(rs, 1);
  rs += __shfl_xor(rs, 2);
  rs += __shfl_xor(rs, 4);
  rs += __shfl_xor(rs, 8);
  if (j == 0) rowsum[i] = rs;
  __syncthreads();
  float nrm = 0.f;
#pragma unroll
  for (int r = 0; r < MDIM; ++r) nrm = fmaxf(nrm, rowsum[r]);
  // scaling exponent: nrm / 2^s <= 0.5
  int s = (nrm > 1e-30f) ? (ilogbf(nrm) + 2) : 0;
  if (s < 0) s = 0;

  const float b = ldexpf(a, -s);
  const float ident = (i == j) ? 1.0f : 0.0f;
  A[tid] = b;
  T[tid] = ident;
  __syncthreads();

  // Horner-Taylor: for k = K..1: T = I + (B @ T) / k
  for (int k = 8; k >= 1; --k) {
    float acc = 0.f;
#pragma unroll
    for (int c = 0; c < MDIM; ++c) acc += A[i * MDIM + c] * T[c * MDIM + j];
    __syncthreads();
    T[tid] = ident + acc * (1.0f / (float)k);
    __syncthreads();
  }

  // square s times
  for (int k = 0; k < s; ++k) {
    float acc = 0.f;
#pragma unroll
    for (int c = 0; c < MDIM; ++c) acc += T[i * MDIM + c] * T[c * MDIM + j];
    __syncthreads();
    T[tid] = acc;
    __syncthreads();
  }

  E[(size_t)bt * MELEMS + tid] = T[tid];
}

// ---------------- Kernel 2: out[t,n,:] = E[t] @ x[n,:] ----------------
// 1024 blocks = 256 t-pairs x 4 row-quarters. Thread (nl = tid>>2, i4 = tid&3)
// holds E[t0] and E[t0+1] fragment rows in 32 float4 registers (loaded once,
// LLC-resident) and streams 64 row-steps: each x row-load feeds TWO dots and
// TWO contiguous 1 KB wave-stores. Loads for step k+1 issue BEFORE the stores
// of step k (vmcnt never drains the HBM stores). No LDS, no barriers.
__global__ __launch_bounds__(256, 2) void apply_kernel(
    const float* __restrict__ E,  /* (T,16,16) */
    const float* __restrict__ x,  /* (N,16)    */
    float* __restrict__ out,      /* (T,N,16)  */
    int N) {
  const int blk = blockIdx.x;
  const int tp  = blk >> 2;                    // t-pair index: t0 = 2*tp
  const int tid = threadIdx.x;
  const int i4 = tid & 3;
  const int nl = tid >> 2;

  // E[t0], E[t0+1] fragment rows -> 32 float4 registers (once per block)
  float4 e0[16], e1[16];
  {
    const float4* __restrict__ Er0 = (const float4*)(E + (size_t)(2 * tp) * MELEMS);
    const float4* __restrict__ Er1 = (const float4*)(E + (size_t)(2 * tp + 1) * MELEMS);
#pragma unroll
    for (int k = 0; k < 4; ++k)
#pragma unroll
      for (int q = 0; q < 4; ++q) {
        e0[k * 4 + q] = Er0[(i4 * 4 + k) * 4 + q];
        e1[k * 4 + q] = Er1[(i4 * 4 + k) * 4 + q];
      }
  }

  const size_t base = (size_t)(blk & 3) * ROWS_PER_BLOCK;  // row base
  const float4* __restrict__ xin = (const float4*)x;
  const size_t slice = (size_t)N * MDIM;                   // floats per t-slice
  float4* __restrict__ op0 = (float4*)(out + (size_t)(2 * tp) * slice + base * MDIM);
  float4* __restrict__ op1 = (float4*)(out + (size_t)(2 * tp + 1) * slice + base * MDIM);

  float4 xa0, xa1, xa2, xa3, xb0, xb1, xb2, xb3;

#define LOADX(d0, d1, d2, d3, k) do {                         \
    const size_t b_ = (base + nl + (size_t)(k) * 64) * 4;     \
    d0 = xin[b_ + 0]; d1 = xin[b_ + 1];                       \
    d2 = xin[b_ + 2]; d3 = xin[b_ + 3];                       \
  } while (0)

#define DOT(o, e, x0, x1, x2, x3) do {                                     \
    _Pragma("unroll")                                                      \
    for (int r = 0; r < 4; ++r) {                                          \
      const float4 ea = e[r * 4 + 0], eb = e[r * 4 + 1];                   \
      const float4 ec = e[r * 4 + 2], ed = e[r * 4 + 3];                   \
      o[r] = ea.x * x0.x + ea.y * x0.y + ea.z * x0.z + ea.w * x0.w         \
           + eb.x * x1.x + eb.y * x1.y + eb.z * x1.z + eb.w * x1.w         \
           + ec.x * x2.x + ec.y * x2.y + ec.z * x2.z + ec.w * x2.w         \
           + ed.x * x3.x + ed.y * x3.y + ed.z * x3.z + ed.w * x3.w;        \
    }                                                                      \
  } while (0)

  LOADX(xa0, xa1, xa2, xa3, 0);
#pragma unroll 2
  for (int k = 0; k < KSTEPS; k += 2) {
    float o[4], p[4];
    // step k (in xa): prefetch k+1 into xb BEFORE the stores of step k
    LOADX(xb0, xb1, xb2, xb3, k + 1);
    DOT(o, e0, xa0, xa1, xa2, xa3);
    DOT(p, e1, xa0, xa1, xa2, xa3);
    op0[k * 256 + tid] = make_float4(o[0], o[1], o[2], o[3]);
    op1[k * 256 + tid] = make_float4(p[0], p[1], p[2], p[3]);
    // step k+1 (in xb): prefetch k+2 into xa BEFORE the stores of step k+1
    if (k + 2 < KSTEPS) LOADX(xa0, xa1, xa2, xa3, k + 2);
    DOT(o, e0, xb0, xb1, xb2, xb3);
    DOT(p, e1, xb0, xb1, xb2, xb3);
    op0[(k + 1) * 256 + tid] = make_float4(o[0], o[1], o[2], o[3]);
    op1[(k + 1) * 256 + tid] = make_float4(p[0], p[1], p[2], p[3]);
  }
#undef LOADX
#undef DOT
}

extern "C" void kernel_launch(void* const* d_in, const int* in_sizes, int n_in,
                              void* d_out, int out_size, void* d_ws, size_t ws_size,
                              hipStream_t stream) {
  const float* x     = (const float*)d_in[0];
  const float* t     = (const float*)d_in[1];
  const float* omega = (const float*)d_in[2];
  const float* M     = (const float*)d_in[3];
  const float* M0    = (const float*)d_in[4];
  float* out = (float*)d_out;

  const int N = in_sizes[0] / MDIM;   // 16384
  const int T = in_sizes[1];          // 512

  float* E = (float*)d_ws;            // T*256 floats = 512 KB

  expm_kernel<<<T, 256, 0, stream>>>(t, omega, M, M0, E);

  apply_kernel<<<(T / 2) * QUARTERS, 256, 0, stream>>>(E, x, out, N);
}